// Round 7
// baseline (222.596 us; speedup 1.0000x reference)
//
#include <hip/hip_runtime.h>

typedef _Float16 half8  __attribute__((ext_vector_type(8)));
typedef _Float16 half4v __attribute__((ext_vector_type(4)));
typedef _Float16 half2v __attribute__((ext_vector_type(2)));
typedef float    floatx4 __attribute__((ext_vector_type(4)));
typedef float    float2v __attribute__((ext_vector_type(2)));

static constexpr float INV2PI = 0.15915494309189535f;  // fold rad->rev into weights
static constexpr float RLOG   = 3.82843f;

// act(a), a in revolutions: x0 = 0.5+0.5cos -> two logistic iters.
// Algebra: p = x0(1-x0) = 0.25 - 0.25 c^2;  out = R^2 * p * (1 - R*p).
__device__ __forceinline__ float act_rev(float a) {
    float c = __builtin_amdgcn_cosf(a);
    float qq = c * c;
    float p = __builtin_fmaf(qq, -0.25f, 0.25f);
    float w = __builtin_fmaf(p, -RLOG, 1.0f);
    return (RLOG * RLOG * p) * w;
}

// Two C-frags (tiles t and t+2) -> one next-layer B-frag, no cat/mov shuffle.
__device__ __forceinline__ half8 act8(floatx4 a, floatx4 b) {
    float2v c0 = { __builtin_amdgcn_cosf(a[0]), __builtin_amdgcn_cosf(a[1]) };
    float2v c1 = { __builtin_amdgcn_cosf(a[2]), __builtin_amdgcn_cosf(a[3]) };
    float2v c2 = { __builtin_amdgcn_cosf(b[0]), __builtin_amdgcn_cosf(b[1]) };
    float2v c3 = { __builtin_amdgcn_cosf(b[2]), __builtin_amdgcn_cosf(b[3]) };
    float2v q0 = c0*c0, q1 = c1*c1, q2 = c2*c2, q3 = c3*c3;
    float2v p0 = __builtin_elementwise_fma(q0, (float2v)(-0.25f), (float2v)(0.25f));
    float2v p1 = __builtin_elementwise_fma(q1, (float2v)(-0.25f), (float2v)(0.25f));
    float2v p2 = __builtin_elementwise_fma(q2, (float2v)(-0.25f), (float2v)(0.25f));
    float2v p3 = __builtin_elementwise_fma(q3, (float2v)(-0.25f), (float2v)(0.25f));
    float2v w0 = __builtin_elementwise_fma(p0, (float2v)(-RLOG), (float2v)(1.0f));
    float2v w1 = __builtin_elementwise_fma(p1, (float2v)(-RLOG), (float2v)(1.0f));
    float2v w2 = __builtin_elementwise_fma(p2, (float2v)(-RLOG), (float2v)(1.0f));
    float2v w3 = __builtin_elementwise_fma(p3, (float2v)(-RLOG), (float2v)(1.0f));
    const float R2 = RLOG * RLOG;
    float2v h0 = (p0*R2)*w0, h1 = (p1*R2)*w1, h2 = (p2*R2)*w2, h3 = (p3*R2)*w3;
    half2v e0 = __builtin_bit_cast(half2v, __builtin_amdgcn_cvt_pkrtz(h0.x, h0.y));
    half2v e1 = __builtin_bit_cast(half2v, __builtin_amdgcn_cvt_pkrtz(h1.x, h1.y));
    half2v e2 = __builtin_bit_cast(half2v, __builtin_amdgcn_cvt_pkrtz(h2.x, h2.y));
    half2v e3 = __builtin_bit_cast(half2v, __builtin_amdgcn_cvt_pkrtz(h3.x, h3.y));
    half4v lo = __builtin_shufflevector(e0, e1, 0, 1, 2, 3);
    half4v hi = __builtin_shufflevector(e2, e3, 0, 1, 2, 3);
    return __builtin_shufflevector(lo, hi, 0, 1, 2, 3, 4, 5, 6, 7);
}

// Non-hoistable f16->f32 (volatile asm defeats LICM so packed-f16 biases stay
// 2 regs each instead of being expanded to 32 live f32 regs by the compiler).
__device__ __forceinline__ float cvt_use(_Float16 h) {
    float f;
    asm volatile("v_cvt_f32_f16 %0, %1" : "=v"(f) : "v"(h));
    return f;
}
__device__ __forceinline__ floatx4 bias4(half4v b) {
    floatx4 r = { cvt_use(b[0]), cvt_use(b[1]), cvt_use(b[2]), cvt_use(b[3]) };
    return r;
}

// Register-resident MLP chain on native 16x16x32 f16 MFMA.
// State: B-frag half8 per tile-pair; next layer's weight COLUMNS permuted by
//   sigma: k-slot (c, q, j) -> neuron (j<4 ? 16c+4q+j : 16(c+2)+4q+j-4)
// so act8(acc_t, acc_{t+2}) IS the next B-frag: zero-instruction transitions.
// launch_bounds(256,3): ~170-reg cap -> 3 waves/SIMD (R5/R6 were stuck at 2
// with both waves stalled on the serial mfma->act chain ~40% of cycles).
// Slim footprint (~155 total): f16-packed b2/b3 (+asm-volatile cvt at use),
// SGPR b4, no tile jam, no cat shuffles.
__global__ __launch_bounds__(256, 3) void mlp_fused(
    const float* __restrict__ x,
    const float* __restrict__ W1, const float* __restrict__ b1,
    const float* __restrict__ W2, const float* __restrict__ b2,
    const float* __restrict__ W3, const float* __restrict__ b3,
    const float* __restrict__ W4, const float* __restrict__ b4,
    float* __restrict__ out, int N)
{
    const int lane = threadIdx.x & 63;
    const int m    = lane & 15;   // sample / C col / A row
    const int q    = lane >> 4;   // quad
    const float s  = INV2PI;
    const floatx4 zero4 = {0.0f, 0.0f, 0.0f, 0.0f};

    // ---------------- per-wave weight prep (reused across 8 tiles) ----------------
    // L1 A-frag (tile t): lanes q==0 hold, for out-neuron n=16t+m, k-slots
    //   [w0h, w0h, w0l, w1h, w1h, w1l, b1h, b1l]   (pairs with xa below)
    half8 w1f[4];
    #pragma unroll
    for (int t = 0; t < 4; ++t) {
        half8 v = {};
        if (q == 0) {
            const int n = 16 * t + m;
            float w0 = W1[2*n] * s, w1 = W1[2*n+1] * s, bb = b1[n] * s;
            _Float16 w0h = (_Float16)w0; float w0l = w0 - (float)w0h;
            _Float16 w1h = (_Float16)w1; float w1l = w1 - (float)w1h;
            _Float16 bh  = (_Float16)bb; float bl  = bb - (float)bh;
            v[0] = w0h; v[1] = w0h; v[2] = (_Float16)w0l;
            v[3] = w1h; v[4] = w1h; v[5] = (_Float16)w1l;
            v[6] = bh;  v[7] = (_Float16)bl;
        }
        w1f[t] = v;
    }

    // L2/L3 A-frags with sigma-permuted columns: two contiguous float4 loads.
    half8 w2f[4][2], w3f[4][2];
    half4v bb2h[4], bb3h[4];                  // packed f16 biases: 2 regs each
    #pragma unroll
    for (int t = 0; t < 4; ++t) {
        const float* r2 = W2 + (16 * t + m) * 64;
        const float* r3 = W3 + (16 * t + m) * 64;
        #pragma unroll
        for (int c = 0; c < 2; ++c) {
            floatx4 lo2 = *(const floatx4*)(r2 + 16 * c + 4 * q);
            floatx4 hi2 = *(const floatx4*)(r2 + 16 * (c + 2) + 4 * q);
            floatx4 lo3 = *(const floatx4*)(r3 + 16 * c + 4 * q);
            floatx4 hi3 = *(const floatx4*)(r3 + 16 * (c + 2) + 4 * q);
            half8 v2, v3;
            #pragma unroll
            for (int j = 0; j < 4; ++j) {
                v2[j]     = (_Float16)(lo2[j] * s);
                v2[4 + j] = (_Float16)(hi2[j] * s);
                v3[j]     = (_Float16)(lo3[j] * s);
                v3[4 + j] = (_Float16)(hi3[j] * s);
            }
            w2f[t][c] = v2;
            w3f[t][c] = v3;
        }
        floatx4 bv2 = *(const floatx4*)(b2 + 16 * t + 4 * q) * s;
        floatx4 bv3 = *(const floatx4*)(b3 + 16 * t + 4 * q) * s;
        bb2h[t] = half4v{ (_Float16)bv2[0], (_Float16)bv2[1], (_Float16)bv2[2], (_Float16)bv2[3] };
        bb3h[t] = half4v{ (_Float16)bv3[0], (_Float16)bv3[1], (_Float16)bv3[2], (_Float16)bv3[3] };
    }

    // L4 A-frag: only out-row m==0 real, same sigma column permutation.
    half8 w4f[2] = {half8{}, half8{}};
    if (m == 0) {
        #pragma unroll
        for (int c = 0; c < 2; ++c) {
            #pragma unroll
            for (int j = 0; j < 8; ++j) {
                int nu = (j < 4) ? (16 * c + 4 * q + j) : (16 * (c + 2) + 4 * q + j - 4);
                w4f[c][j] = (_Float16)(W4[nu] * s);
            }
        }
    }
    const float b4s = b4[0] * s;              // wave-uniform -> SGPR

    const int ntiles = N >> 4;
    const int nwaves = (gridDim.x * blockDim.x) >> 6;
    const int gwave  = (int)(blockIdx.x * blockDim.x + threadIdx.x) >> 6;
    const float2* __restrict__ x2 = (const float2*)x;

    int tile = gwave;
    float2 xv = x2[(tile << 4) + m];          // 1-ahead x prefetch
    while (tile < ntiles) {
        const int nt = tile + nwaves;
        float2 xnext;
        if (nt < ntiles) xnext = x2[(nt << 4) + m];

        // L1 B-frag (lanes q==0): [xh, xl, xh, yh, yl, yh, 1, 1]
        half8 xa = {};
        if (q == 0) {
            _Float16 xh = (_Float16)xv.x; float xl = xv.x - (float)xh;
            _Float16 yh = (_Float16)xv.y; float yl = xv.y - (float)yh;
            xa[0] = xh; xa[1] = (_Float16)xl; xa[2] = xh;
            xa[3] = yh; xa[4] = (_Float16)yl; xa[5] = yh;
            xa[6] = (_Float16)1.0f; xa[7] = (_Float16)1.0f;
        }

        // ---- layer 1 ----
        floatx4 a0 = __builtin_amdgcn_mfma_f32_16x16x32_f16(w1f[0], xa, zero4, 0, 0, 0);
        floatx4 a1 = __builtin_amdgcn_mfma_f32_16x16x32_f16(w1f[1], xa, zero4, 0, 0, 0);
        floatx4 a2 = __builtin_amdgcn_mfma_f32_16x16x32_f16(w1f[2], xa, zero4, 0, 0, 0);
        floatx4 a3 = __builtin_amdgcn_mfma_f32_16x16x32_f16(w1f[3], xa, zero4, 0, 0, 0);
        half8 B0 = act8(a0, a2);
        half8 B1 = act8(a1, a3);

        // ---- layer 2 ----
        a0 = __builtin_amdgcn_mfma_f32_16x16x32_f16(w2f[0][0], B0, bias4(bb2h[0]), 0, 0, 0);
        a1 = __builtin_amdgcn_mfma_f32_16x16x32_f16(w2f[1][0], B0, bias4(bb2h[1]), 0, 0, 0);
        a2 = __builtin_amdgcn_mfma_f32_16x16x32_f16(w2f[2][0], B0, bias4(bb2h[2]), 0, 0, 0);
        a3 = __builtin_amdgcn_mfma_f32_16x16x32_f16(w2f[3][0], B0, bias4(bb2h[3]), 0, 0, 0);
        a0 = __builtin_amdgcn_mfma_f32_16x16x32_f16(w2f[0][1], B1, a0, 0, 0, 0);
        a1 = __builtin_amdgcn_mfma_f32_16x16x32_f16(w2f[1][1], B1, a1, 0, 0, 0);
        a2 = __builtin_amdgcn_mfma_f32_16x16x32_f16(w2f[2][1], B1, a2, 0, 0, 0);
        a3 = __builtin_amdgcn_mfma_f32_16x16x32_f16(w2f[3][1], B1, a3, 0, 0, 0);
        half8 C0 = act8(a0, a2);
        half8 C1 = act8(a1, a3);

        // ---- layer 3 ----
        a0 = __builtin_amdgcn_mfma_f32_16x16x32_f16(w3f[0][0], C0, bias4(bb3h[0]), 0, 0, 0);
        a1 = __builtin_amdgcn_mfma_f32_16x16x32_f16(w3f[1][0], C0, bias4(bb3h[1]), 0, 0, 0);
        a2 = __builtin_amdgcn_mfma_f32_16x16x32_f16(w3f[2][0], C0, bias4(bb3h[2]), 0, 0, 0);
        a3 = __builtin_amdgcn_mfma_f32_16x16x32_f16(w3f[3][0], C0, bias4(bb3h[3]), 0, 0, 0);
        a0 = __builtin_amdgcn_mfma_f32_16x16x32_f16(w3f[0][1], C1, a0, 0, 0, 0);
        a1 = __builtin_amdgcn_mfma_f32_16x16x32_f16(w3f[1][1], C1, a1, 0, 0, 0);
        a2 = __builtin_amdgcn_mfma_f32_16x16x32_f16(w3f[2][1], C1, a2, 0, 0, 0);
        a3 = __builtin_amdgcn_mfma_f32_16x16x32_f16(w3f[3][1], C1, a3, 0, 0, 0);
        half8 D0 = act8(a0, a2);
        half8 D1 = act8(a1, a3);

        // ---- layer 4 + store (bias from SGPR, added post-MFMA) ----
        floatx4 a4 = __builtin_amdgcn_mfma_f32_16x16x32_f16(w4f[0], D0, zero4, 0, 0, 0);
        a4 = __builtin_amdgcn_mfma_f32_16x16x32_f16(w4f[1], D1, a4, 0, 0, 0);
        if (q == 0)
            out[(tile << 4) + m] = act_rev(a4[0] + b4s);

        xv = xnext;
        tile = nt;
    }
}

extern "C" void kernel_launch(void* const* d_in, const int* in_sizes, int n_in,
                              void* d_out, int out_size, void* d_ws, size_t ws_size,
                              hipStream_t stream) {
    const float* x  = (const float*)d_in[0];
    const float* W1 = (const float*)d_in[1];
    const float* b1 = (const float*)d_in[2];
    const float* W2 = (const float*)d_in[3];
    const float* b2 = (const float*)d_in[4];
    const float* W3 = (const float*)d_in[5];
    const float* b3 = (const float*)d_in[6];
    const float* W4 = (const float*)d_in[7];
    const float* b4 = (const float*)d_in[8];
    float* out = (float*)d_out;
    const int N = out_size;          // 2097152, divisible by 16

    // 4096 blocks x 4 waves = 16384 waves; 131072 tiles -> exactly 8 tiles/wave.
    mlp_fused<<<dim3(4096), dim3(256), 0, stream>>>(x, W1, b1, W2, b2, W3, b3, W4, b4, out, N);
}